// Round 3
// baseline (384.213 us; speedup 1.0000x reference)
//
#include <hip/hip_runtime.h>

typedef __bf16 bf16x8 __attribute__((ext_vector_type(8)));
typedef float f32x4 __attribute__((ext_vector_type(4)));
typedef unsigned short u16x8 __attribute__((ext_vector_type(8)));
typedef unsigned short u16x4 __attribute__((ext_vector_type(4)));

__device__ __forceinline__ unsigned short f2bf_bits(float f) {
  unsigned u = __float_as_uint(f);
  return (unsigned short)((u + 0x7FFFu + ((u >> 16) & 1u)) >> 16);
}

__device__ __forceinline__ float exp2_amd(float x) {
  return __builtin_amdgcn_exp2f(x);
}

__device__ __forceinline__ void gload16(const void* g, void* l) {
  __builtin_amdgcn_global_load_lds(
      (const __attribute__((address_space(1))) unsigned int*)g,
      (__attribute__((address_space(3))) unsigned int*)l, 16, 0, 0);
}

// ---------------- weight convert + transpose: src[R][C] f32 -> dst[C][R] bf16
__global__ __launch_bounds__(256) void wconv_t(const float* __restrict__ src,
                                               unsigned short* __restrict__ dst,
                                               int R, int C) {
  __shared__ float tile[32][33];
  const int tx = threadIdx.x & 31, ty = threadIdx.x >> 5;
  const size_t c0 = (size_t)blockIdx.x * 32, r0 = (size_t)blockIdx.y * 32;
#pragma unroll
  for (int i = 0; i < 4; i++)
    tile[ty + i * 8][tx] = src[(r0 + ty + i * 8) * C + c0 + tx];
  __syncthreads();
#pragma unroll
  for (int i = 0; i < 4; i++) {
    int c = ty + i * 8;
    dst[(c0 + c) * R + r0 + tx] = f2bf_bits(tile[tx][c]);
  }
}

// ---------------- LayerNorm: x[row][1024] f32 -> out bf16
__global__ __launch_bounds__(256) void ln_k(const float* __restrict__ x,
                                            const float* __restrict__ g,
                                            const float* __restrict__ be,
                                            unsigned short* __restrict__ o) {
  const int row = blockIdx.x, tid = threadIdx.x;
  const float4 v = ((const float4*)(x + (size_t)row * 1024))[tid];
  float s = v.x + v.y + v.z + v.w;
  float s2 = v.x * v.x + v.y * v.y + v.z * v.z + v.w * v.w;
#pragma unroll
  for (int m = 1; m < 64; m <<= 1) {
    s += __shfl_xor(s, m);
    s2 += __shfl_xor(s2, m);
  }
  __shared__ float red[8];
  const int w = tid >> 6;
  if ((tid & 63) == 0) { red[w] = s; red[4 + w] = s2; }
  __syncthreads();
  s = red[0] + red[1] + red[2] + red[3];
  s2 = red[4] + red[5] + red[6] + red[7];
  const float mu = s * (1.f / 1024.f);
  const float rs_ = rsqrtf(s2 * (1.f / 1024.f) - mu * mu + 1e-5f);
  const float4 gg = ((const float4*)g)[tid];
  const float4 bb = ((const float4*)be)[tid];
  u16x4 pack;
  pack.x = f2bf_bits((v.x - mu) * rs_ * gg.x + bb.x);
  pack.y = f2bf_bits((v.y - mu) * rs_ * gg.y + bb.y);
  pack.z = f2bf_bits((v.z - mu) * rs_ * gg.z + bb.z);
  pack.w = f2bf_bits((v.w - mu) * rs_ * gg.w + bb.w);
  *(u16x4*)(o + (size_t)row * 1024 + tid * 4) = pack;
}

// ---------------- GEMM: C[M][N] = epi(A[M][K] @ Bt[N][K]^T + bias [+ res])
// EPI 0: bf16 store. 1: +bias +res(f32), f32 store. 2: +bias, relu, bf16 store.
template <int EPI>
__global__ __launch_bounds__(256) void gemm_bt(
    const unsigned short* __restrict__ A, const unsigned short* __restrict__ Bt,
    const float* __restrict__ bias, const float* __restrict__ res,
    void* __restrict__ Cv, int M, int N, int K) {
  __shared__ __align__(16) unsigned short As[128 * 64];
  __shared__ __align__(16) unsigned short Bs[128 * 64];
  const int tid = threadIdx.x, lane = tid & 63, w = tid >> 6;
  const int lo = lane & 15, hi = lane >> 4;
  const int l8 = lane >> 3, l7 = lane & 7;
  const int scol = ((l7 ^ l8) << 3);  // swizzled source col (elements)
  const size_t rowBase = (size_t)blockIdx.y * 128;
  const size_t colBase = (size_t)blockIdx.x * 128;
  f32x4 acc[4][4];
#pragma unroll
  for (int i = 0; i < 4; i++)
#pragma unroll
    for (int j = 0; j < 4; j++) acc[i][j] = (f32x4){0.f, 0.f, 0.f, 0.f};
  const int wr = (w >> 1) * 64, wc = (w & 1) * 64;
  const unsigned short* aSrc = A + (rowBase + (size_t)w * 32 + l8) * K + scol;
  const unsigned short* bSrc = Bt + (colBase + (size_t)w * 32 + l8) * K + scol;
  for (int kb = 0; kb < K; kb += 64) {
    __syncthreads();
#pragma unroll
    for (int c = 0; c < 4; c++) {
      gload16(aSrc + (size_t)c * 8 * K + kb, &As[(w * 4 + c) * 512]);
      gload16(bSrc + (size_t)c * 8 * K + kb, &Bs[(w * 4 + c) * 512]);
    }
    __syncthreads();
#pragma unroll
    for (int ks = 0; ks < 2; ks++) {
      bf16x8 af[4], bfr[4];
      const int kbyte = ks * 64 + (hi << 4);
#pragma unroll
      for (int i = 0; i < 4; i++) {
        const int ar = wr + i * 16 + lo;
        af[i] = *(const bf16x8*)((const char*)As + ar * 128 + (kbyte ^ ((ar & 7) << 4)));
        const int br = wc + i * 16 + lo;
        bfr[i] = *(const bf16x8*)((const char*)Bs + br * 128 + (kbyte ^ ((br & 7) << 4)));
      }
#pragma unroll
      for (int i = 0; i < 4; i++)
#pragma unroll
        for (int j = 0; j < 4; j++)
          acc[i][j] = __builtin_amdgcn_mfma_f32_16x16x32_bf16(af[i], bfr[j], acc[i][j], 0, 0, 0);
    }
  }
#pragma unroll
  for (int i = 0; i < 4; i++) {
#pragma unroll
    for (int r = 0; r < 4; r++) {
      const size_t row = rowBase + wr + i * 16 + hi * 4 + r;
#pragma unroll
      for (int j = 0; j < 4; j++) {
        const size_t col = colBase + wc + j * 16 + lo;
        float v = acc[i][j][r];
        if (EPI >= 1) v += bias[col];
        if (EPI == 1) {
          ((float*)Cv)[row * N + col] = v + res[row * N + col];
        } else if (EPI == 2) {
          ((unsigned short*)Cv)[row * N + col] = f2bf_bits(fmaxf(v, 0.f));
        } else {
          ((unsigned short*)Cv)[row * N + col] = f2bf_bits(v);
        }
      }
    }
  }
}

// ---------------- flash attention: grid (S/64, H, N); 4 waves, 16 q-rows each
// Double-buffered K/Vt LDS, exp2-domain softmax, defer-max, lane-partial l.
// K tile = 64 rows = 8 gload16 chunks total -> 2 chunks per wave.
__global__ __launch_bounds__(256) void attn_k(const unsigned short* __restrict__ Q,
                                              const unsigned short* __restrict__ K,
                                              const unsigned short* __restrict__ V,
                                              unsigned short* __restrict__ O) {
  __shared__ __align__(16) unsigned short Ks[2][64 * 64];
  __shared__ __align__(16) unsigned short Vt[2][64 * 64];  // Vt[d][kv] (swizzled)
  __shared__ __align__(16) unsigned short Ps[4][16 * 64];
  const int tid = threadIdx.x, lane = tid & 63, w = tid >> 6;
  const int lo = lane & 15, hi = lane >> 4;
  const int l8 = lane >> 3, l7 = lane & 7;
  const int scol = ((l7 ^ l8) << 3);
  const int h = blockIdx.y, n = blockIdx.z;
  const size_t tRow0 = (size_t)n * 2048;
  const int colBase = h * 64;
  const float SC = 0.125f * 1.44269504f;  // (1/sqrt(64)) * log2(e)

  // Q fragments (row = lo, k contiguous)
  const unsigned short* qrow = Q + (tRow0 + blockIdx.x * 64 + w * 16 + lo) * 1024 + colBase;
  const bf16x8 qf0 = *(const bf16x8*)(qrow + hi * 8);
  const bf16x8 qf1 = *(const bf16x8*)(qrow + 32 + hi * 8);
  float m2[4], l_r[4];
  f32x4 oacc[4];
#pragma unroll
  for (int r = 0; r < 4; r++) { m2[r] = -1e30f; l_r[r] = 0.f; }
#pragma unroll
  for (int d = 0; d < 4; d++) oacc[d] = (f32x4){0.f, 0.f, 0.f, 0.f};

  // per-thread V staging coords
  const int vkv = tid & 63, vdg = tid >> 6;
  const unsigned short* vbase = V + (tRow0 + vkv) * 1024 + colBase + vdg * 16;
  // per-thread K staging base: wave w owns rows w*16 .. w*16+15 (2 chunks of 8)
  const unsigned short* kbase = K + (tRow0 + (size_t)w * 16 + l8) * 1024 + colBase + scol;

  // ---- prologue: stage tile 0 into buffer 0
  u16x8 v0 = *(const u16x8*)(vbase);
  u16x8 v1 = *(const u16x8*)(vbase + 8);
#pragma unroll
  for (int c = 0; c < 2; c++)
    gload16(kbase + (size_t)c * 8 * 1024, &Ks[0][(w * 2 + c) * 512]);
  {
    char* vt = (char*)Vt[0];
#pragma unroll
    for (int j = 0; j < 8; j++) {
      *(unsigned short*)(vt + (vdg * 16 + j) * 128 + ((vkv * 2) ^ (j << 4))) = v0[j];
      *(unsigned short*)(vt + (vdg * 16 + 8 + j) * 128 + ((vkv * 2) ^ (j << 4))) = v1[j];
    }
  }
  __syncthreads();

  for (int t = 0; t < 32; ++t) {
    const int cur = t & 1;
    // ---- issue next-tile loads early (hide under compute)
    if (t < 31) {
      v0 = *(const u16x8*)(vbase + (size_t)(t + 1) * 64 * 1024);
      v1 = *(const u16x8*)(vbase + (size_t)(t + 1) * 64 * 1024 + 8);
#pragma unroll
      for (int c = 0; c < 2; c++)
        gload16(kbase + ((size_t)(t + 1) * 64 + c * 8) * 1024, &Ks[cur ^ 1][(w * 2 + c) * 512]);
    }
    // ---- QK^T from Ks[cur]
    f32x4 s[4];
    const char* ksb = (const char*)Ks[cur];
    __builtin_amdgcn_s_setprio(1);
#pragma unroll
    for (int f = 0; f < 4; f++) {
      s[f] = (f32x4){0.f, 0.f, 0.f, 0.f};
      const int kr = f * 16 + lo;
      const bf16x8 b0 = *(const bf16x8*)(ksb + kr * 128 + ((hi * 16) ^ ((kr & 7) << 4)));
      const bf16x8 b1 = *(const bf16x8*)(ksb + kr * 128 + ((64 + hi * 16) ^ ((kr & 7) << 4)));
      s[f] = __builtin_amdgcn_mfma_f32_16x16x32_bf16(qf0, b0, s[f], 0, 0, 0);
      s[f] = __builtin_amdgcn_mfma_f32_16x16x32_bf16(qf1, b1, s[f], 0, 0, 0);
    }
    __builtin_amdgcn_s_setprio(0);
    // ---- online softmax in exp2 domain (rows q = hi*4+r, spread over 16 lo-lanes)
    float mx2[4];
#pragma unroll
    for (int r = 0; r < 4; r++) {
      float mx = fmaxf(fmaxf(s[0][r], s[1][r]), fmaxf(s[2][r], s[3][r]));
      mx = fmaxf(mx, __shfl_xor(mx, 1));
      mx = fmaxf(mx, __shfl_xor(mx, 2));
      mx = fmaxf(mx, __shfl_xor(mx, 4));
      mx = fmaxf(mx, __shfl_xor(mx, 8));
      mx2[r] = mx * SC;
    }
    const bool need = (mx2[0] > m2[0] + 8.f) || (mx2[1] > m2[1] + 8.f) ||
                      (mx2[2] > m2[2] + 8.f) || (mx2[3] > m2[3] + 8.f);
    if (__any(need)) {
#pragma unroll
      for (int r = 0; r < 4; r++) {
        const float mn = fmaxf(m2[r], mx2[r]);
        const float al = exp2_amd(m2[r] - mn);
        l_r[r] *= al;
        m2[r] = mn;
#pragma unroll
        for (int d = 0; d < 4; d++) oacc[d][r] *= al;
      }
    }
    // ---- P = exp2(s*SC - m2), lane-partial l, P -> LDS (bf16, swizzled)
    char* psb = (char*)&Ps[w][0];
#pragma unroll
    for (int r = 0; r < 4; r++) {
      const float p0 = exp2_amd(fmaf(s[0][r], SC, -m2[r]));
      const float p1 = exp2_amd(fmaf(s[1][r], SC, -m2[r]));
      const float p2 = exp2_amd(fmaf(s[2][r], SC, -m2[r]));
      const float p3 = exp2_amd(fmaf(s[3][r], SC, -m2[r]));
      l_r[r] += (p0 + p1) + (p2 + p3);
      const int q = hi * 4 + r;
      const int qsw = (q & 7) << 4;
      *(unsigned short*)(psb + q * 128 + (((0 * 16 + lo) * 2) ^ qsw)) = f2bf_bits(p0);
      *(unsigned short*)(psb + q * 128 + (((1 * 16 + lo) * 2) ^ qsw)) = f2bf_bits(p1);
      *(unsigned short*)(psb + q * 128 + (((2 * 16 + lo) * 2) ^ qsw)) = f2bf_bits(p2);
      *(unsigned short*)(psb + q * 128 + (((3 * 16 + lo) * 2) ^ qsw)) = f2bf_bits(p3);
    }
    asm volatile("" ::: "memory");  // order LDS P writes before reads (same wave)
    // ---- PV from Vt[cur]
    __builtin_amdgcn_s_setprio(1);
#pragma unroll
    for (int ks = 0; ks < 2; ks++) {
      const int kbyte = ks * 64 + (hi << 4);
      const bf16x8 ap = *(const bf16x8*)(psb + lo * 128 + (kbyte ^ ((lo & 7) << 4)));
#pragma unroll
      for (int d = 0; d < 4; d++) {
        const int dr = d * 16 + lo;
        const bf16x8 bv = *(const bf16x8*)((const char*)Vt[cur] + dr * 128 + (kbyte ^ ((dr & 7) << 4)));
        oacc[d] = __builtin_amdgcn_mfma_f32_16x16x32_bf16(ap, bv, oacc[d], 0, 0, 0);
      }
    }
    __builtin_amdgcn_s_setprio(0);
    // ---- write next V tile into the other buffer (reg staging arrived by now)
    if (t < 31) {
      char* vt = (char*)Vt[cur ^ 1];
#pragma unroll
      for (int j = 0; j < 8; j++) {
        *(unsigned short*)(vt + (vdg * 16 + j) * 128 + ((vkv * 2) ^ (j << 4))) = v0[j];
        *(unsigned short*)(vt + (vdg * 16 + 8 + j) * 128 + ((vkv * 2) ^ (j << 4))) = v1[j];
      }
    }
    __syncthreads();  // staging of next tile complete; cur reads done
  }
  // ---- epilogue: reduce l across the 16-lane row group, normalize, store
#pragma unroll
  for (int r = 0; r < 4; r++) {
    float l = l_r[r];
    l += __shfl_xor(l, 1);
    l += __shfl_xor(l, 2);
    l += __shfl_xor(l, 4);
    l += __shfl_xor(l, 8);
    const float inv = 1.f / l;
    const size_t row = tRow0 + blockIdx.x * 64 + w * 16 + hi * 4 + r;
#pragma unroll
    for (int d = 0; d < 4; d++)
      O[row * 1024 + colBase + d * 16 + lo] = f2bf_bits(oacc[d][r] * inv);
  }
}

extern "C" void kernel_launch(void* const* d_in, const int* in_sizes, int n_in,
                              void* d_out, int out_size, void* d_ws, size_t ws_size,
                              hipStream_t stream) {
  (void)in_sizes; (void)n_in; (void)out_size; (void)ws_size;
  const float* x   = (const float*)d_in[0];
  const float* w_q = (const float*)d_in[2];
  const float* w_k = (const float*)d_in[3];
  const float* w_v = (const float*)d_in[4];
  const float* w_0 = (const float*)d_in[5];
  const float* b_0 = (const float*)d_in[6];
  const float* w_1 = (const float*)d_in[7];
  const float* b_1 = (const float*)d_in[8];
  const float* w_2 = (const float*)d_in[9];
  const float* b_2 = (const float*)d_in[10];
  const float* g_1 = (const float*)d_in[11];
  const float* be_1 = (const float*)d_in[12];
  const float* g_2 = (const float*)d_in[13];
  const float* be_2 = (const float*)d_in[14];

  char* ws = (char*)d_ws;
  size_t off = 0;
  auto alloc = [&](size_t bytes) {
    void* p = ws + off;
    off += (bytes + 255) & ~(size_t)255;
    return p;
  };
  const size_t MB = 1024 * 1024;
  unsigned short* wt_q = (unsigned short*)alloc(2 * MB);
  unsigned short* wt_k = (unsigned short*)alloc(2 * MB);
  unsigned short* wt_v = (unsigned short*)alloc(2 * MB);
  unsigned short* wt_0 = (unsigned short*)alloc(2 * MB);
  unsigned short* wt_1 = (unsigned short*)alloc(8 * MB);   // [4096][1024]
  unsigned short* wt_2 = (unsigned short*)alloc(8 * MB);   // [1024][4096]
  unsigned short* xn   = (unsigned short*)alloc(8 * MB);   // [4096][1024]
  unsigned short* Qb   = (unsigned short*)alloc(8 * MB);
  unsigned short* Kb   = (unsigned short*)alloc(8 * MB);
  unsigned short* Vb   = (unsigned short*)alloc(8 * MB);
  unsigned short* aO   = (unsigned short*)alloc(8 * MB);
  float*          x1f  = (float*)alloc(16 * MB);           // [4096][1024] f32
  unsigned short* ff1  = (unsigned short*)alloc(32 * MB);  // [4096][4096]

  // weights -> bf16 transposed
  wconv_t<<<dim3(32, 32), 256, 0, stream>>>(w_q, wt_q, 1024, 1024);
  wconv_t<<<dim3(32, 32), 256, 0, stream>>>(w_k, wt_k, 1024, 1024);
  wconv_t<<<dim3(32, 32), 256, 0, stream>>>(w_v, wt_v, 1024, 1024);
  wconv_t<<<dim3(32, 32), 256, 0, stream>>>(w_0, wt_0, 1024, 1024);
  wconv_t<<<dim3(128, 32), 256, 0, stream>>>(w_1, wt_1, 1024, 4096);
  wconv_t<<<dim3(32, 128), 256, 0, stream>>>(w_2, wt_2, 4096, 1024);

  // LN1
  ln_k<<<4096, 256, 0, stream>>>(x, g_1, be_1, xn);
  // QKV projections
  gemm_bt<0><<<dim3(8, 32), 256, 0, stream>>>(xn, wt_q, nullptr, nullptr, Qb, 4096, 1024, 1024);
  gemm_bt<0><<<dim3(8, 32), 256, 0, stream>>>(xn, wt_k, nullptr, nullptr, Kb, 4096, 1024, 1024);
  gemm_bt<0><<<dim3(8, 32), 256, 0, stream>>>(xn, wt_v, nullptr, nullptr, Vb, 4096, 1024, 1024);
  // attention
  attn_k<<<dim3(32, 16, 2), 256, 0, stream>>>(Qb, Kb, Vb, aO);
  // output proj + residual -> x1 (f32)
  gemm_bt<1><<<dim3(8, 32), 256, 0, stream>>>(aO, wt_0, b_0, x, x1f, 4096, 1024, 1024);
  // LN2
  ln_k<<<4096, 256, 0, stream>>>(x1f, g_2, be_2, xn);
  // FF1 + relu
  gemm_bt<2><<<dim3(32, 32), 256, 0, stream>>>(xn, wt_1, b_1, nullptr, ff1, 4096, 4096, 1024);
  // FF2 + bias + residual -> out (f32)
  gemm_bt<1><<<dim3(8, 32), 256, 0, stream>>>(ff1, wt_2, b_2, x1f, (float*)d_out, 4096, 1024, 4096);
}

// Round 4
// 301.943 us; speedup vs baseline: 1.2725x; 1.2725x over previous
//
#include <hip/hip_runtime.h>

typedef __bf16 bf16x8 __attribute__((ext_vector_type(8)));
typedef float f32x4 __attribute__((ext_vector_type(4)));
typedef unsigned short u16x8 __attribute__((ext_vector_type(8)));
typedef unsigned short u16x4 __attribute__((ext_vector_type(4)));

__device__ __forceinline__ unsigned short f2bf_bits(float f) {
  unsigned u = __float_as_uint(f);
  return (unsigned short)((u + 0x7FFFu + ((u >> 16) & 1u)) >> 16);
}

__device__ __forceinline__ float exp2_amd(float x) {
  return __builtin_amdgcn_exp2f(x);
}

__device__ __forceinline__ unsigned cvt_pk_bf16(float a, float b) {
  unsigned r;
  asm("v_cvt_pk_bf16_f32 %0, %1, %2" : "=v"(r) : "v"(a), "v"(b));
  return r;
}

__device__ __forceinline__ void gload16(const void* g, void* l) {
  __builtin_amdgcn_global_load_lds(
      (const __attribute__((address_space(1))) unsigned int*)g,
      (__attribute__((address_space(3))) unsigned int*)l, 16, 0, 0);
}

// ---------------- weight convert + transpose: src[R][C] f32 -> dst[C][R] bf16
__global__ __launch_bounds__(256) void wconv_t(const float* __restrict__ src,
                                               unsigned short* __restrict__ dst,
                                               int R, int C) {
  __shared__ float tile[32][33];
  const int tx = threadIdx.x & 31, ty = threadIdx.x >> 5;
  const size_t c0 = (size_t)blockIdx.x * 32, r0 = (size_t)blockIdx.y * 32;
#pragma unroll
  for (int i = 0; i < 4; i++)
    tile[ty + i * 8][tx] = src[(r0 + ty + i * 8) * C + c0 + tx];
  __syncthreads();
#pragma unroll
  for (int i = 0; i < 4; i++) {
    int c = ty + i * 8;
    dst[(c0 + c) * R + r0 + tx] = f2bf_bits(tile[tx][c]);
  }
}

// ---------------- LayerNorm: x[row][1024] f32 -> out bf16
__global__ __launch_bounds__(256) void ln_k(const float* __restrict__ x,
                                            const float* __restrict__ g,
                                            const float* __restrict__ be,
                                            unsigned short* __restrict__ o) {
  const int row = blockIdx.x, tid = threadIdx.x;
  const float4 v = ((const float4*)(x + (size_t)row * 1024))[tid];
  float s = v.x + v.y + v.z + v.w;
  float s2 = v.x * v.x + v.y * v.y + v.z * v.z + v.w * v.w;
#pragma unroll
  for (int m = 1; m < 64; m <<= 1) {
    s += __shfl_xor(s, m);
    s2 += __shfl_xor(s2, m);
  }
  __shared__ float red[8];
  const int w = tid >> 6;
  if ((tid & 63) == 0) { red[w] = s; red[4 + w] = s2; }
  __syncthreads();
  s = red[0] + red[1] + red[2] + red[3];
  s2 = red[4] + red[5] + red[6] + red[7];
  const float mu = s * (1.f / 1024.f);
  const float rs_ = rsqrtf(s2 * (1.f / 1024.f) - mu * mu + 1e-5f);
  const float4 gg = ((const float4*)g)[tid];
  const float4 bb = ((const float4*)be)[tid];
  u16x4 pack;
  pack.x = f2bf_bits((v.x - mu) * rs_ * gg.x + bb.x);
  pack.y = f2bf_bits((v.y - mu) * rs_ * gg.y + bb.y);
  pack.z = f2bf_bits((v.z - mu) * rs_ * gg.z + bb.z);
  pack.w = f2bf_bits((v.w - mu) * rs_ * gg.w + bb.w);
  *(u16x4*)(o + (size_t)row * 1024 + tid * 4) = pack;
}

// ---------------- GEMM: C[M][N] = epi(A[M][K] @ Bt[N][K]^T + bias [+ res])
// EPI 0: bf16 store. 1: +bias +res(f32), f32 store. 2: +bias, relu, bf16 store.
template <int EPI>
__global__ __launch_bounds__(256) void gemm_bt(
    const unsigned short* __restrict__ A, const unsigned short* __restrict__ Bt,
    const float* __restrict__ bias, const float* __restrict__ res,
    void* __restrict__ Cv, int M, int N, int K) {
  __shared__ __align__(16) unsigned short As[128 * 64];
  __shared__ __align__(16) unsigned short Bs[128 * 64];
  const int tid = threadIdx.x, lane = tid & 63, w = tid >> 6;
  const int lo = lane & 15, hi = lane >> 4;
  const int l8 = lane >> 3, l7 = lane & 7;
  const int scol = ((l7 ^ l8) << 3);  // swizzled source col (elements)
  const size_t rowBase = (size_t)blockIdx.y * 128;
  const size_t colBase = (size_t)blockIdx.x * 128;
  f32x4 acc[4][4];
#pragma unroll
  for (int i = 0; i < 4; i++)
#pragma unroll
    for (int j = 0; j < 4; j++) acc[i][j] = (f32x4){0.f, 0.f, 0.f, 0.f};
  const int wr = (w >> 1) * 64, wc = (w & 1) * 64;
  const unsigned short* aSrc = A + (rowBase + (size_t)w * 32 + l8) * K + scol;
  const unsigned short* bSrc = Bt + (colBase + (size_t)w * 32 + l8) * K + scol;
  for (int kb = 0; kb < K; kb += 64) {
    __syncthreads();
#pragma unroll
    for (int c = 0; c < 4; c++) {
      gload16(aSrc + (size_t)c * 8 * K + kb, &As[(w * 4 + c) * 512]);
      gload16(bSrc + (size_t)c * 8 * K + kb, &Bs[(w * 4 + c) * 512]);
    }
    __syncthreads();
#pragma unroll
    for (int ks = 0; ks < 2; ks++) {
      bf16x8 af[4], bfr[4];
      const int kbyte = ks * 64 + (hi << 4);
#pragma unroll
      for (int i = 0; i < 4; i++) {
        const int ar = wr + i * 16 + lo;
        af[i] = *(const bf16x8*)((const char*)As + ar * 128 + (kbyte ^ ((ar & 7) << 4)));
        const int br = wc + i * 16 + lo;
        bfr[i] = *(const bf16x8*)((const char*)Bs + br * 128 + (kbyte ^ ((br & 7) << 4)));
      }
#pragma unroll
      for (int i = 0; i < 4; i++)
#pragma unroll
        for (int j = 0; j < 4; j++)
          acc[i][j] = __builtin_amdgcn_mfma_f32_16x16x32_bf16(af[i], bfr[j], acc[i][j], 0, 0, 0);
    }
  }
#pragma unroll
  for (int i = 0; i < 4; i++) {
#pragma unroll
    for (int r = 0; r < 4; r++) {
      const size_t row = rowBase + wr + i * 16 + hi * 4 + r;
#pragma unroll
      for (int j = 0; j < 4; j++) {
        const size_t col = colBase + wc + j * 16 + lo;
        float v = acc[i][j][r];
        if (EPI >= 1) v += bias[col];
        if (EPI == 1) {
          ((float*)Cv)[row * N + col] = v + res[row * N + col];
        } else if (EPI == 2) {
          ((unsigned short*)Cv)[row * N + col] = f2bf_bits(fmaxf(v, 0.f));
        } else {
          ((unsigned short*)Cv)[row * N + col] = f2bf_bits(v);
        }
      }
    }
  }
}

// ---------------- flash attention: grid (S/64, H, N); 4 waves, 16 q-rows each.
// Swapped QK^T (T12): lane holds P[q=lo][16 kv]; softmax lane-local; P->PV via
// cvt_pk + permlane32_swap + shfl_xor16 (no P LDS). Q/K/V from fused buffer, LD=3072.
__global__ __launch_bounds__(256) void attn_k(const unsigned short* __restrict__ Q,
                                              const unsigned short* __restrict__ K,
                                              const unsigned short* __restrict__ V,
                                              unsigned short* __restrict__ O) {
  __shared__ __align__(16) unsigned short Ks[2][64 * 64];
  __shared__ __align__(16) unsigned short Vt[2][64 * 64];  // Vt[d][kv] (swizzled)
  const int tid = threadIdx.x, lane = tid & 63, w = tid >> 6;
  const int lo = lane & 15, hi = lane >> 4;
  const int l8 = lane >> 3, l7 = lane & 7;
  const int scol = ((l7 ^ l8) << 3);
  const int h = blockIdx.y, n = blockIdx.z;
  const size_t tRow0 = (size_t)n * 2048;
  const int colBase = h * 64;
  const int LD = 3072;
  const float SC = 0.125f * 1.44269504f;  // (1/sqrt(64)) * log2(e)

  // Q fragments (B-operand: col=q=lo, k=d contiguous)
  const unsigned short* qrow = Q + (tRow0 + blockIdx.x * 64 + w * 16 + lo) * LD + colBase;
  const bf16x8 qf0 = *(const bf16x8*)(qrow + hi * 8);
  const bf16x8 qf1 = *(const bf16x8*)(qrow + 32 + hi * 8);
  float m2 = -1e30f, l_r = 0.f;  // per-lane, for q-row = w*16 + lo
  f32x4 oacc[4];
#pragma unroll
  for (int d = 0; d < 4; d++) oacc[d] = (f32x4){0.f, 0.f, 0.f, 0.f};

  // per-thread V staging coords
  const int vkv = tid & 63, vdg = tid >> 6;
  const unsigned short* vbase = V + (tRow0 + vkv) * LD + colBase + vdg * 16;
  // per-thread K staging base: wave w owns rows w*16 .. w*16+15 (2 chunks of 8)
  const unsigned short* kbase = K + (tRow0 + (size_t)w * 16 + l8) * LD + colBase + scol;

  // ---- prologue: stage tile 0 into buffer 0
  u16x8 v0 = *(const u16x8*)(vbase);
  u16x8 v1 = *(const u16x8*)(vbase + 8);
#pragma unroll
  for (int c = 0; c < 2; c++)
    gload16(kbase + (size_t)c * 8 * LD, &Ks[0][(w * 2 + c) * 512]);
  {
    char* vt = (char*)Vt[0];
#pragma unroll
    for (int j = 0; j < 8; j++) {
      *(unsigned short*)(vt + (vdg * 16 + j) * 128 + ((vkv * 2) ^ (j << 4))) = v0[j];
      *(unsigned short*)(vt + (vdg * 16 + 8 + j) * 128 + ((vkv * 2) ^ (j << 4))) = v1[j];
    }
  }
  __syncthreads();

  for (int t = 0; t < 32; ++t) {
    const int cur = t & 1;
    // ---- issue next-tile loads early (hide under compute)
    if (t < 31) {
      v0 = *(const u16x8*)(vbase + (size_t)(t + 1) * 64 * LD);
      v1 = *(const u16x8*)(vbase + (size_t)(t + 1) * 64 * LD + 8);
#pragma unroll
      for (int c = 0; c < 2; c++)
        gload16(kbase + ((size_t)(t + 1) * 64 + c * 8) * LD, &Ks[cur ^ 1][(w * 2 + c) * 512]);
    }
    // ---- swapped QK^T from Ks[cur]: s[f][r] = P[kv=f*16+hi*4+r][q=lo]
    f32x4 s[4];
    const char* ksb = (const char*)Ks[cur];
    __builtin_amdgcn_s_setprio(1);
#pragma unroll
    for (int f = 0; f < 4; f++) {
      const int kr = f * 16 + lo;
      const bf16x8 b0 = *(const bf16x8*)(ksb + kr * 128 + ((hi * 16) ^ ((kr & 7) << 4)));
      const bf16x8 b1 = *(const bf16x8*)(ksb + kr * 128 + ((64 + hi * 16) ^ ((kr & 7) << 4)));
      s[f] = __builtin_amdgcn_mfma_f32_16x16x32_bf16(b0, qf0, (f32x4){0.f, 0.f, 0.f, 0.f}, 0, 0, 0);
      s[f] = __builtin_amdgcn_mfma_f32_16x16x32_bf16(b1, qf1, s[f], 0, 0, 0);
    }
    __builtin_amdgcn_s_setprio(0);
    // ---- softmax, lane-local for q=lo (16 values), reduce across hi-groups
    float mx = fmaxf(fmaxf(fmaxf(s[0][0], s[0][1]), fmaxf(s[0][2], s[0][3])),
                     fmaxf(fmaxf(s[1][0], s[1][1]), fmaxf(s[1][2], s[1][3])));
    mx = fmaxf(mx, fmaxf(fmaxf(fmaxf(s[2][0], s[2][1]), fmaxf(s[2][2], s[2][3])),
                         fmaxf(fmaxf(s[3][0], s[3][1]), fmaxf(s[3][2], s[3][3]))));
    mx = fmaxf(mx, __shfl_xor(mx, 16));
    mx = fmaxf(mx, __shfl_xor(mx, 32));
    const float mx2v = mx * SC;
    if (__any(mx2v > m2 + 8.f)) {  // defer-max (T13)
      const float mn = fmaxf(m2, mx2v);
      const float al = exp2_amd(m2 - mn);
      l_r *= al;
      m2 = mn;
#pragma unroll
      for (int r = 0; r < 4; r++) {
        const float alr = __shfl(al, hi * 4 + r);  // al for q-row hi*4+r
#pragma unroll
        for (int d = 0; d < 4; d++) oacc[d][r] *= alr;
      }
    }
    // ---- P = exp2(s*SC - m2); lane-partial l; pack to bf16 pairs
    float p[4][4];
    float lsum = 0.f;
#pragma unroll
    for (int f = 0; f < 4; f++)
#pragma unroll
      for (int r = 0; r < 4; r++) {
        p[f][r] = exp2_amd(fmaf(s[f][r], SC, -m2));
        lsum += p[f][r];
      }
    l_r += lsum;
    unsigned W2[4][2];
#pragma unroll
    for (int f = 0; f < 4; f++) {
      W2[f][0] = cvt_pk_bf16(p[f][0], p[f][1]);
      W2[f][1] = cvt_pk_bf16(p[f][2], p[f][3]);
    }
    // ---- redistribute P to A-fragment layout + PV
    __builtin_amdgcn_s_setprio(1);
#pragma unroll
    for (int ks = 0; ks < 2; ks++) {
      unsigned wa[2], wb[2];
#pragma unroll
      for (int hh = 0; hh < 2; hh++) {
        unsigned X = W2[ks * 2][hh], Y = W2[ks * 2 + 1][hh];
        asm("v_permlane32_swap_b32 %0, %1" : "+v"(X), "+v"(Y));
        // X = [Xlo, Ylo], Y = [Xhi, Yhi]
        const unsigned Bx = __shfl_xor((int)Y, 16);
        const unsigned Ax = __shfl_xor((int)X, 16);
        wa[hh] = (hi & 1) ? Bx : X;
        wb[hh] = (hi & 1) ? Y : Ax;
      }
      union { unsigned u[4]; bf16x8 v; } apu;
      apu.u[0] = wa[0]; apu.u[1] = wa[1]; apu.u[2] = wb[0]; apu.u[3] = wb[1];
      const int kbyte = ks * 64 + (hi << 4);
#pragma unroll
      for (int d = 0; d < 4; d++) {
        const int dr = d * 16 + lo;
        const bf16x8 bv = *(const bf16x8*)((const char*)Vt[cur] + dr * 128 + (kbyte ^ ((dr & 7) << 4)));
        oacc[d] = __builtin_amdgcn_mfma_f32_16x16x32_bf16(apu.v, bv, oacc[d], 0, 0, 0);
      }
    }
    __builtin_amdgcn_s_setprio(0);
    // ---- write next V tile into the other buffer (reg staging arrived by now)
    if (t < 31) {
      char* vt = (char*)Vt[cur ^ 1];
#pragma unroll
      for (int j = 0; j < 8; j++) {
        *(unsigned short*)(vt + (vdg * 16 + j) * 128 + ((vkv * 2) ^ (j << 4))) = v0[j];
        *(unsigned short*)(vt + (vdg * 16 + 8 + j) * 128 + ((vkv * 2) ^ (j << 4))) = v1[j];
      }
    }
    __syncthreads();  // staging of next tile complete; cur reads done
  }
  // ---- epilogue: reduce l across hi-groups (q=lo), broadcast inv to oacc rows
  float l = l_r;
  l += __shfl_xor(l, 16);
  l += __shfl_xor(l, 32);
  const float inv = 1.f / l;  // for q-row = w*16 + lo
#pragma unroll
  for (int r = 0; r < 4; r++) {
    const float invr = __shfl(inv, hi * 4 + r);
    const size_t row = tRow0 + blockIdx.x * 64 + w * 16 + hi * 4 + r;
#pragma unroll
    for (int d = 0; d < 4; d++)
      O[row * 1024 + colBase + d * 16 + lo] = f2bf_bits(oacc[d][r] * invr);
  }
}

extern "C" void kernel_launch(void* const* d_in, const int* in_sizes, int n_in,
                              void* d_out, int out_size, void* d_ws, size_t ws_size,
                              hipStream_t stream) {
  (void)in_sizes; (void)n_in; (void)out_size; (void)ws_size;
  const float* x   = (const float*)d_in[0];
  const float* w_q = (const float*)d_in[2];
  const float* w_k = (const float*)d_in[3];
  const float* w_v = (const float*)d_in[4];
  const float* w_0 = (const float*)d_in[5];
  const float* b_0 = (const float*)d_in[6];
  const float* w_1 = (const float*)d_in[7];
  const float* b_1 = (const float*)d_in[8];
  const float* w_2 = (const float*)d_in[9];
  const float* b_2 = (const float*)d_in[10];
  const float* g_1 = (const float*)d_in[11];
  const float* be_1 = (const float*)d_in[12];
  const float* g_2 = (const float*)d_in[13];
  const float* be_2 = (const float*)d_in[14];

  char* ws = (char*)d_ws;
  size_t off = 0;
  auto alloc = [&](size_t bytes) {
    void* p = ws + off;
    off += (bytes + 255) & ~(size_t)255;
    return p;
  };
  const size_t MB = 1024 * 1024;
  // wt_q/wt_k/wt_v contiguous -> fused [3072][1024] Bt for the QKV GEMM
  unsigned short* wt_q = (unsigned short*)alloc(2 * MB);
  unsigned short* wt_k = (unsigned short*)alloc(2 * MB);
  unsigned short* wt_v = (unsigned short*)alloc(2 * MB);
  unsigned short* wt_0 = (unsigned short*)alloc(2 * MB);
  unsigned short* wt_1 = (unsigned short*)alloc(8 * MB);   // [4096][1024]
  unsigned short* wt_2 = (unsigned short*)alloc(8 * MB);   // [1024][4096]
  unsigned short* xn   = (unsigned short*)alloc(8 * MB);   // [4096][1024]
  unsigned short* qkv  = (unsigned short*)alloc(24 * MB);  // [4096][3072]
  unsigned short* aO   = (unsigned short*)alloc(8 * MB);
  float*          x1f  = (float*)alloc(16 * MB);           // [4096][1024] f32
  unsigned short* ff1  = (unsigned short*)alloc(32 * MB);  // [4096][4096]

  // weights -> bf16 transposed
  wconv_t<<<dim3(32, 32), 256, 0, stream>>>(w_q, wt_q, 1024, 1024);
  wconv_t<<<dim3(32, 32), 256, 0, stream>>>(w_k, wt_k, 1024, 1024);
  wconv_t<<<dim3(32, 32), 256, 0, stream>>>(w_v, wt_v, 1024, 1024);
  wconv_t<<<dim3(32, 32), 256, 0, stream>>>(w_0, wt_0, 1024, 1024);
  wconv_t<<<dim3(128, 32), 256, 0, stream>>>(w_1, wt_1, 1024, 4096);
  wconv_t<<<dim3(32, 128), 256, 0, stream>>>(w_2, wt_2, 4096, 1024);

  // LN1
  ln_k<<<4096, 256, 0, stream>>>(x, g_1, be_1, xn);
  // fused QKV projection: [4096][1024] @ [3072][1024]^T -> [4096][3072]
  gemm_bt<0><<<dim3(24, 32), 256, 0, stream>>>(xn, wt_q, nullptr, nullptr, qkv, 4096, 3072, 1024);
  // attention (Q/K/V columns of the fused buffer, row stride 3072)
  attn_k<<<dim3(32, 16, 2), 256, 0, stream>>>(qkv, qkv + 1024, qkv + 2048, aO);
  // output proj + residual -> x1 (f32)
  gemm_bt<1><<<dim3(8, 32), 256, 0, stream>>>(aO, wt_0, b_0, x, x1f, 4096, 1024, 1024);
  // LN2
  ln_k<<<4096, 256, 0, stream>>>(x1f, g_2, be_2, xn);
  // FF1 + relu
  gemm_bt<2><<<dim3(32, 32), 256, 0, stream>>>(xn, wt_1, b_1, nullptr, ff1, 4096, 4096, 1024);
  // FF2 + bias + residual -> out (f32)
  gemm_bt<1><<<dim3(8, 32), 256, 0, stream>>>(ff1, wt_2, b_2, x1f, (float*)d_out, 4096, 1024, 4096);
}

// Round 5
// 284.757 us; speedup vs baseline: 1.3493x; 1.0604x over previous
//
#include <hip/hip_runtime.h>

typedef __bf16 bf16x8 __attribute__((ext_vector_type(8)));
typedef float f32x4 __attribute__((ext_vector_type(4)));
typedef unsigned short u16x8 __attribute__((ext_vector_type(8)));
typedef unsigned short u16x4 __attribute__((ext_vector_type(4)));

__device__ __forceinline__ unsigned short f2bf_bits(float f) {
  unsigned u = __float_as_uint(f);
  return (unsigned short)((u + 0x7FFFu + ((u >> 16) & 1u)) >> 16);
}

__device__ __forceinline__ float exp2_amd(float x) {
  return __builtin_amdgcn_exp2f(x);
}

__device__ __forceinline__ unsigned cvt_pk_bf16(float a, float b) {
  unsigned r;
  asm("v_cvt_pk_bf16_f32 %0, %1, %2" : "=v"(r) : "v"(a), "v"(b));
  return r;
}

__device__ __forceinline__ void gload16(const void* g, void* l) {
  __builtin_amdgcn_global_load_lds(
      (const __attribute__((address_space(1))) unsigned int*)g,
      (__attribute__((address_space(3))) unsigned int*)l, 16, 0, 0);
}

// ---------------- weight convert + transpose: src[R][C] f32 -> dst[C][R] bf16
__global__ __launch_bounds__(256) void wconv_t(const float* __restrict__ src,
                                               unsigned short* __restrict__ dst,
                                               int R, int C) {
  __shared__ float tile[32][33];
  const int tx = threadIdx.x & 31, ty = threadIdx.x >> 5;
  const size_t c0 = (size_t)blockIdx.x * 32, r0 = (size_t)blockIdx.y * 32;
#pragma unroll
  for (int i = 0; i < 4; i++)
    tile[ty + i * 8][tx] = src[(r0 + ty + i * 8) * C + c0 + tx];
  __syncthreads();
#pragma unroll
  for (int i = 0; i < 4; i++) {
    int c = ty + i * 8;
    dst[(c0 + c) * R + r0 + tx] = f2bf_bits(tile[tx][c]);
  }
}

// ---------------- LayerNorm: x[row][1024] f32 -> out bf16
__global__ __launch_bounds__(256) void ln_k(const float* __restrict__ x,
                                            const float* __restrict__ g,
                                            const float* __restrict__ be,
                                            unsigned short* __restrict__ o) {
  const int row = blockIdx.x, tid = threadIdx.x;
  const float4 v = ((const float4*)(x + (size_t)row * 1024))[tid];
  float s = v.x + v.y + v.z + v.w;
  float s2 = v.x * v.x + v.y * v.y + v.z * v.z + v.w * v.w;
#pragma unroll
  for (int m = 1; m < 64; m <<= 1) {
    s += __shfl_xor(s, m);
    s2 += __shfl_xor(s2, m);
  }
  __shared__ float red[8];
  const int w = tid >> 6;
  if ((tid & 63) == 0) { red[w] = s; red[4 + w] = s2; }
  __syncthreads();
  s = red[0] + red[1] + red[2] + red[3];
  s2 = red[4] + red[5] + red[6] + red[7];
  const float mu = s * (1.f / 1024.f);
  const float rs_ = rsqrtf(s2 * (1.f / 1024.f) - mu * mu + 1e-5f);
  const float4 gg = ((const float4*)g)[tid];
  const float4 bb = ((const float4*)be)[tid];
  u16x4 pack;
  pack.x = f2bf_bits((v.x - mu) * rs_ * gg.x + bb.x);
  pack.y = f2bf_bits((v.y - mu) * rs_ * gg.y + bb.y);
  pack.z = f2bf_bits((v.z - mu) * rs_ * gg.z + bb.z);
  pack.w = f2bf_bits((v.w - mu) * rs_ * gg.w + bb.w);
  *(u16x4*)(o + (size_t)row * 1024 + tid * 4) = pack;
}

// ---------------- GEMM: C[M][N] = epi(A[M][K] @ Bt[N][K]^T + bias [+ res])
// EPI 0: bf16 store. 1: +bias +res(f32), f32 store. 2: +bias, relu, bf16 store.
// Counted-vmcnt double-buffered pipeline (T3/T4) + XCD swizzle (T1) + setprio (T5).
template <int EPI>
__global__ __launch_bounds__(256) void gemm_bt(
    const unsigned short* __restrict__ A, const unsigned short* __restrict__ Bt,
    const float* __restrict__ bias, const float* __restrict__ res,
    void* __restrict__ Cv, int M, int N, int K) {
  __shared__ __align__(16) unsigned short As[2][128 * 64];
  __shared__ __align__(16) unsigned short Bs[2][128 * 64];
  const int tid = threadIdx.x, lane = tid & 63, w = tid >> 6;
  const int lo = lane & 15, hi = lane >> 4;
  const int l8 = lane >> 3, l7 = lane & 7;
  const int scol = ((l7 ^ l8) << 3);  // swizzled source col (elements)
  // T1: XCD-aware block swizzle (all our grids have nwg % 8 == 0)
  const int nwg = gridDim.x * gridDim.y;
  int bid = blockIdx.y * gridDim.x + blockIdx.x;
  if ((nwg & 7) == 0) bid = (bid & 7) * (nwg >> 3) + (bid >> 3);
  const int bx = bid % gridDim.x, by = bid / gridDim.x;
  const size_t rowBase = (size_t)by * 128;
  const size_t colBase = (size_t)bx * 128;
  f32x4 acc[4][4];
#pragma unroll
  for (int i = 0; i < 4; i++)
#pragma unroll
    for (int j = 0; j < 4; j++) acc[i][j] = (f32x4){0.f, 0.f, 0.f, 0.f};
  const int wr = (w >> 1) * 64, wc = (w & 1) * 64;
  const unsigned short* aSrc = A + (rowBase + (size_t)w * 32 + l8) * K + scol;
  const unsigned short* bSrc = Bt + (colBase + (size_t)w * 32 + l8) * K + scol;

  const int NT = K >> 6;
  // stage K-tile t into LDS buffer buf (8 gload16 per thread)
  auto stage = [&](int t, int buf) {
    const int kb = t << 6;
#pragma unroll
    for (int c = 0; c < 4; c++) {
      gload16(aSrc + (size_t)c * 8 * K + kb, &As[buf][(w * 4 + c) * 512]);
      gload16(bSrc + (size_t)c * 8 * K + kb, &Bs[buf][(w * 4 + c) * 512]);
    }
  };

  // prologue: tiles 0 and 1 in flight; wait for tile 0 (8 of tile 1 remain)
  stage(0, 0);
  stage(1, 1);
  asm volatile("s_waitcnt vmcnt(8)" ::: "memory");
  __builtin_amdgcn_s_barrier();

  for (int t = 0; t < NT; ++t) {
    const int cur = t & 1;
    const char* asb = (const char*)As[cur];
    const char* bsb = (const char*)Bs[cur];
    __builtin_amdgcn_s_setprio(1);
#pragma unroll
    for (int ks = 0; ks < 2; ks++) {
      bf16x8 af[4], bfr[4];
      const int kbyte = ks * 64 + (hi << 4);
#pragma unroll
      for (int i = 0; i < 4; i++) {
        const int ar = wr + i * 16 + lo;
        af[i] = *(const bf16x8*)(asb + ar * 128 + (kbyte ^ ((ar & 7) << 4)));
        const int br = wc + i * 16 + lo;
        bfr[i] = *(const bf16x8*)(bsb + br * 128 + (kbyte ^ ((br & 7) << 4)));
      }
#pragma unroll
      for (int i = 0; i < 4; i++)
#pragma unroll
        for (int j = 0; j < 4; j++)
          acc[i][j] = __builtin_amdgcn_mfma_f32_16x16x32_bf16(af[i], bfr[j], acc[i][j], 0, 0, 0);
    }
    __builtin_amdgcn_s_setprio(0);
    // all my LDS reads complete (data in regs) before signaling done-with-buf[cur]
    asm volatile("s_waitcnt lgkmcnt(0)" ::: "memory");
    __builtin_amdgcn_s_barrier();  // B1: everyone done reading buf[cur]
    if (t + 2 < NT) {
      stage(t + 2, cur);
      // wait tile t+1's 8 loads (oldest); tile t+2's 8 stay in flight
      asm volatile("s_waitcnt vmcnt(8)" ::: "memory");
    } else {
      asm volatile("s_waitcnt vmcnt(0)" ::: "memory");
    }
    __builtin_amdgcn_s_barrier();  // B2: buf[cur^1] fully staged for all waves
  }

#pragma unroll
  for (int i = 0; i < 4; i++) {
#pragma unroll
    for (int r = 0; r < 4; r++) {
      const size_t row = rowBase + wr + i * 16 + hi * 4 + r;
#pragma unroll
      for (int j = 0; j < 4; j++) {
        const size_t col = colBase + wc + j * 16 + lo;
        float v = acc[i][j][r];
        if (EPI >= 1) v += bias[col];
        if (EPI == 1) {
          ((float*)Cv)[row * N + col] = v + res[row * N + col];
        } else if (EPI == 2) {
          ((unsigned short*)Cv)[row * N + col] = f2bf_bits(fmaxf(v, 0.f));
        } else {
          ((unsigned short*)Cv)[row * N + col] = f2bf_bits(v);
        }
      }
    }
  }
}

// ---------------- flash attention: grid (S/64, H, N); 4 waves, 16 q-rows each.
// Swapped QK^T (T12): lane holds P[q=lo][16 kv]; softmax lane-local; P->PV via
// cvt_pk + permlane32_swap + shfl_xor16 (no P LDS). Q/K/V from fused buffer, LD=3072.
__global__ __launch_bounds__(256) void attn_k(const unsigned short* __restrict__ Q,
                                              const unsigned short* __restrict__ K,
                                              const unsigned short* __restrict__ V,
                                              unsigned short* __restrict__ O) {
  __shared__ __align__(16) unsigned short Ks[2][64 * 64];
  __shared__ __align__(16) unsigned short Vt[2][64 * 64];  // Vt[d][kv] (swizzled)
  const int tid = threadIdx.x, lane = tid & 63, w = tid >> 6;
  const int lo = lane & 15, hi = lane >> 4;
  const int l8 = lane >> 3, l7 = lane & 7;
  const int scol = ((l7 ^ l8) << 3);
  const int h = blockIdx.y, n = blockIdx.z;
  const size_t tRow0 = (size_t)n * 2048;
  const int colBase = h * 64;
  const int LD = 3072;
  const float SC = 0.125f * 1.44269504f;  // (1/sqrt(64)) * log2(e)

  // Q fragments (B-operand: col=q=lo, k=d contiguous)
  const unsigned short* qrow = Q + (tRow0 + blockIdx.x * 64 + w * 16 + lo) * LD + colBase;
  const bf16x8 qf0 = *(const bf16x8*)(qrow + hi * 8);
  const bf16x8 qf1 = *(const bf16x8*)(qrow + 32 + hi * 8);
  float m2 = -1e30f, l_r = 0.f;  // per-lane, for q-row = w*16 + lo
  f32x4 oacc[4];
#pragma unroll
  for (int d = 0; d < 4; d++) oacc[d] = (f32x4){0.f, 0.f, 0.f, 0.f};

  // per-thread V staging coords
  const int vkv = tid & 63, vdg = tid >> 6;
  const unsigned short* vbase = V + (tRow0 + vkv) * LD + colBase + vdg * 16;
  // per-thread K staging base: wave w owns rows w*16 .. w*16+15 (2 chunks of 8)
  const unsigned short* kbase = K + (tRow0 + (size_t)w * 16 + l8) * LD + colBase + scol;

  // ---- prologue: stage tile 0 into buffer 0
  u16x8 v0 = *(const u16x8*)(vbase);
  u16x8 v1 = *(const u16x8*)(vbase + 8);
#pragma unroll
  for (int c = 0; c < 2; c++)
    gload16(kbase + (size_t)c * 8 * LD, &Ks[0][(w * 2 + c) * 512]);
  {
    char* vt = (char*)Vt[0];
#pragma unroll
    for (int j = 0; j < 8; j++) {
      *(unsigned short*)(vt + (vdg * 16 + j) * 128 + ((vkv * 2) ^ (j << 4))) = v0[j];
      *(unsigned short*)(vt + (vdg * 16 + 8 + j) * 128 + ((vkv * 2) ^ (j << 4))) = v1[j];
    }
  }
  __syncthreads();

  for (int t = 0; t < 32; ++t) {
    const int cur = t & 1;
    // ---- issue next-tile loads early (hide under compute)
    if (t < 31) {
      v0 = *(const u16x8*)(vbase + (size_t)(t + 1) * 64 * LD);
      v1 = *(const u16x8*)(vbase + (size_t)(t + 1) * 64 * LD + 8);
#pragma unroll
      for (int c = 0; c < 2; c++)
        gload16(kbase + ((size_t)(t + 1) * 64 + c * 8) * LD, &Ks[cur ^ 1][(w * 2 + c) * 512]);
    }
    // ---- swapped QK^T from Ks[cur]: s[f][r] = P[kv=f*16+hi*4+r][q=lo]
    f32x4 s[4];
    const char* ksb = (const char*)Ks[cur];
    __builtin_amdgcn_s_setprio(1);
#pragma unroll
    for (int f = 0; f < 4; f++) {
      const int kr = f * 16 + lo;
      const bf16x8 b0 = *(const bf16x8*)(ksb + kr * 128 + ((hi * 16) ^ ((kr & 7) << 4)));
      const bf16x8 b1 = *(const bf16x8*)(ksb + kr * 128 + ((64 + hi * 16) ^ ((kr & 7) << 4)));
      s[f] = __builtin_amdgcn_mfma_f32_16x16x32_bf16(b0, qf0, (f32x4){0.f, 0.f, 0.f, 0.f}, 0, 0, 0);
      s[f] = __builtin_amdgcn_mfma_f32_16x16x32_bf16(b1, qf1, s[f], 0, 0, 0);
    }
    __builtin_amdgcn_s_setprio(0);
    // ---- softmax, lane-local for q=lo (16 values), reduce across hi-groups
    float mx = fmaxf(fmaxf(fmaxf(s[0][0], s[0][1]), fmaxf(s[0][2], s[0][3])),
                     fmaxf(fmaxf(s[1][0], s[1][1]), fmaxf(s[1][2], s[1][3])));
    mx = fmaxf(mx, fmaxf(fmaxf(fmaxf(s[2][0], s[2][1]), fmaxf(s[2][2], s[2][3])),
                         fmaxf(fmaxf(s[3][0], s[3][1]), fmaxf(s[3][2], s[3][3]))));
    mx = fmaxf(mx, __shfl_xor(mx, 16));
    mx = fmaxf(mx, __shfl_xor(mx, 32));
    const float mx2v = mx * SC;
    if (__any(mx2v > m2 + 8.f)) {  // defer-max (T13)
      const float mn = fmaxf(m2, mx2v);
      const float al = exp2_amd(m2 - mn);
      l_r *= al;
      m2 = mn;
#pragma unroll
      for (int r = 0; r < 4; r++) {
        const float alr = __shfl(al, hi * 4 + r);  // al for q-row hi*4+r
#pragma unroll
        for (int d = 0; d < 4; d++) oacc[d][r] *= alr;
      }
    }
    // ---- P = exp2(s*SC - m2); lane-partial l; pack to bf16 pairs
    float p[4][4];
    float lsum = 0.f;
#pragma unroll
    for (int f = 0; f < 4; f++)
#pragma unroll
      for (int r = 0; r < 4; r++) {
        p[f][r] = exp2_amd(fmaf(s[f][r], SC, -m2));
        lsum += p[f][r];
      }
    l_r += lsum;
    unsigned W2[4][2];
#pragma unroll
    for (int f = 0; f < 4; f++) {
      W2[f][0] = cvt_pk_bf16(p[f][0], p[f][1]);
      W2[f][1] = cvt_pk_bf16(p[f][2], p[f][3]);
    }
    // ---- redistribute P to A-fragment layout + PV
    __builtin_amdgcn_s_setprio(1);
#pragma unroll
    for (int ks = 0; ks < 2; ks++) {
      unsigned wa[2], wb[2];
#pragma unroll
      for (int hh = 0; hh < 2; hh++) {
        unsigned X = W2[ks * 2][hh], Y = W2[ks * 2 + 1][hh];
        asm("v_permlane32_swap_b32 %0, %1" : "+v"(X), "+v"(Y));
        // X = [Xlo, Ylo], Y = [Xhi, Yhi]
        const unsigned Bx = __shfl_xor((int)Y, 16);
        const unsigned Ax = __shfl_xor((int)X, 16);
        wa[hh] = (hi & 1) ? Bx : X;
        wb[hh] = (hi & 1) ? Y : Ax;
      }
      union { unsigned u[4]; bf16x8 v; } apu;
      apu.u[0] = wa[0]; apu.u[1] = wa[1]; apu.u[2] = wb[0]; apu.u[3] = wb[1];
      const int kbyte = ks * 64 + (hi << 4);
#pragma unroll
      for (int d = 0; d < 4; d++) {
        const int dr = d * 16 + lo;
        const bf16x8 bv = *(const bf16x8*)((const char*)Vt[cur] + dr * 128 + (kbyte ^ ((dr & 7) << 4)));
        oacc[d] = __builtin_amdgcn_mfma_f32_16x16x32_bf16(apu.v, bv, oacc[d], 0, 0, 0);
      }
    }
    __builtin_amdgcn_s_setprio(0);
    // ---- write next V tile into the other buffer (reg staging arrived by now)
    if (t < 31) {
      char* vt = (char*)Vt[cur ^ 1];
#pragma unroll
      for (int j = 0; j < 8; j++) {
        *(unsigned short*)(vt + (vdg * 16 + j) * 128 + ((vkv * 2) ^ (j << 4))) = v0[j];
        *(unsigned short*)(vt + (vdg * 16 + 8 + j) * 128 + ((vkv * 2) ^ (j << 4))) = v1[j];
      }
    }
    __syncthreads();  // staging of next tile complete; cur reads done
  }
  // ---- epilogue: reduce l across hi-groups (q=lo), broadcast inv to oacc rows
  float l = l_r;
  l += __shfl_xor(l, 16);
  l += __shfl_xor(l, 32);
  const float inv = 1.f / l;  // for q-row = w*16 + lo
#pragma unroll
  for (int r = 0; r < 4; r++) {
    const float invr = __shfl(inv, hi * 4 + r);
    const size_t row = tRow0 + blockIdx.x * 64 + w * 16 + hi * 4 + r;
#pragma unroll
    for (int d = 0; d < 4; d++)
      O[row * 1024 + colBase + d * 16 + lo] = f2bf_bits(oacc[d][r] * invr);
  }
}

extern "C" void kernel_launch(void* const* d_in, const int* in_sizes, int n_in,
                              void* d_out, int out_size, void* d_ws, size_t ws_size,
                              hipStream_t stream) {
  (void)in_sizes; (void)n_in; (void)out_size; (void)ws_size;
  const float* x   = (const float*)d_in[0];
  const float* w_q = (const float*)d_in[2];
  const float* w_k = (const float*)d_in[3];
  const float* w_v = (const float*)d_in[4];
  const float* w_0 = (const float*)d_in[5];
  const float* b_0 = (const float*)d_in[6];
  const float* w_1 = (const float*)d_in[7];
  const float* b_1 = (const float*)d_in[8];
  const float* w_2 = (const float*)d_in[9];
  const float* b_2 = (const float*)d_in[10];
  const float* g_1 = (const float*)d_in[11];
  const float* be_1 = (const float*)d_in[12];
  const float* g_2 = (const float*)d_in[13];
  const float* be_2 = (const float*)d_in[14];

  char* ws = (char*)d_ws;
  size_t off = 0;
  auto alloc = [&](size_t bytes) {
    void* p = ws + off;
    off += (bytes + 255) & ~(size_t)255;
    return p;
  };
  const size_t MB = 1024 * 1024;
  // wt_q/wt_k/wt_v contiguous -> fused [3072][1024] Bt for the QKV GEMM
  unsigned short* wt_q = (unsigned short*)alloc(2 * MB);
  unsigned short* wt_k = (unsigned short*)alloc(2 * MB);
  unsigned short* wt_v = (unsigned short*)alloc(2 * MB);
  unsigned short* wt_0 = (unsigned short*)alloc(2 * MB);
  unsigned short* wt_1 = (unsigned short*)alloc(8 * MB);   // [4096][1024]
  unsigned short* wt_2 = (unsigned short*)alloc(8 * MB);   // [1024][4096]
  unsigned short* xn   = (unsigned short*)alloc(8 * MB);   // [4096][1024]
  unsigned short* qkv  = (unsigned short*)alloc(24 * MB);  // [4096][3072]
  unsigned short* aO   = (unsigned short*)alloc(8 * MB);
  float*          x1f  = (float*)alloc(16 * MB);           // [4096][1024] f32
  unsigned short* ff1  = (unsigned short*)alloc(32 * MB);  // [4096][4096]

  // weights -> bf16 transposed
  wconv_t<<<dim3(32, 32), 256, 0, stream>>>(w_q, wt_q, 1024, 1024);
  wconv_t<<<dim3(32, 32), 256, 0, stream>>>(w_k, wt_k, 1024, 1024);
  wconv_t<<<dim3(32, 32), 256, 0, stream>>>(w_v, wt_v, 1024, 1024);
  wconv_t<<<dim3(32, 32), 256, 0, stream>>>(w_0, wt_0, 1024, 1024);
  wconv_t<<<dim3(128, 32), 256, 0, stream>>>(w_1, wt_1, 1024, 4096);
  wconv_t<<<dim3(32, 128), 256, 0, stream>>>(w_2, wt_2, 4096, 1024);

  // LN1
  ln_k<<<4096, 256, 0, stream>>>(x, g_1, be_1, xn);
  // fused QKV projection: [4096][1024] @ [3072][1024]^T -> [4096][3072]
  gemm_bt<0><<<dim3(24, 32), 256, 0, stream>>>(xn, wt_q, nullptr, nullptr, qkv, 4096, 3072, 1024);
  // attention (Q/K/V columns of the fused buffer, row stride 3072)
  attn_k<<<dim3(32, 16, 2), 256, 0, stream>>>(qkv, qkv + 1024, qkv + 2048, aO);
  // output proj + residual -> x1 (f32)
  gemm_bt<1><<<dim3(8, 32), 256, 0, stream>>>(aO, wt_0, b_0, x, x1f, 4096, 1024, 1024);
  // LN2
  ln_k<<<4096, 256, 0, stream>>>(x1f, g_2, be_2, xn);
  // FF1 + relu
  gemm_bt<2><<<dim3(32, 32), 256, 0, stream>>>(xn, wt_1, b_1, nullptr, ff1, 4096, 4096, 1024);
  // FF2 + bias + residual -> out (f32)
  gemm_bt<1><<<dim3(8, 32), 256, 0, stream>>>(ff1, wt_2, b_2, x1f, (float*)d_out, 4096, 1024, 4096);
}

// Round 6
// 273.961 us; speedup vs baseline: 1.4024x; 1.0394x over previous
//
#include <hip/hip_runtime.h>

typedef __bf16 bf16x8 __attribute__((ext_vector_type(8)));
typedef float f32x4 __attribute__((ext_vector_type(4)));
typedef unsigned short u16x8 __attribute__((ext_vector_type(8)));
typedef unsigned short u16x4 __attribute__((ext_vector_type(4)));

__device__ __forceinline__ unsigned short f2bf_bits(float f) {
  unsigned u = __float_as_uint(f);
  return (unsigned short)((u + 0x7FFFu + ((u >> 16) & 1u)) >> 16);
}

__device__ __forceinline__ float exp2_amd(float x) {
  return __builtin_amdgcn_exp2f(x);
}

__device__ __forceinline__ unsigned cvt_pk_bf16(float a, float b) {
  unsigned r;
  asm("v_cvt_pk_bf16_f32 %0, %1, %2" : "=v"(r) : "v"(a), "v"(b));
  return r;
}

// xor16 / xor32 reductions on the VALU pipe (permlane swap) instead of ds_swizzle
__device__ __forceinline__ float red16_max(float x) {
  unsigned a = __float_as_uint(x), b = a;
  asm("v_permlane16_swap_b32 %0, %1" : "+v"(a), "+v"(b));
  return fmaxf(__uint_as_float(a), __uint_as_float(b));
}
__device__ __forceinline__ float red32_max(float x) {
  unsigned a = __float_as_uint(x), b = a;
  asm("v_permlane32_swap_b32 %0, %1" : "+v"(a), "+v"(b));
  return fmaxf(__uint_as_float(a), __uint_as_float(b));
}
__device__ __forceinline__ float red16_sum(float x) {
  unsigned a = __float_as_uint(x), b = a;
  asm("v_permlane16_swap_b32 %0, %1" : "+v"(a), "+v"(b));
  return __uint_as_float(a) + __uint_as_float(b);
}
__device__ __forceinline__ float red32_sum(float x) {
  unsigned a = __float_as_uint(x), b = a;
  asm("v_permlane32_swap_b32 %0, %1" : "+v"(a), "+v"(b));
  return __uint_as_float(a) + __uint_as_float(b);
}

__device__ __forceinline__ void gload16(const void* g, void* l) {
  __builtin_amdgcn_global_load_lds(
      (const __attribute__((address_space(1))) unsigned int*)g,
      (__attribute__((address_space(3))) unsigned int*)l, 16, 0, 0);
}

// ---------------- weight convert + transpose: src[R][C] f32 -> dst[C][R] bf16
__global__ __launch_bounds__(256) void wconv_t(const float* __restrict__ src,
                                               unsigned short* __restrict__ dst,
                                               int R, int C) {
  __shared__ float tile[32][33];
  const int tx = threadIdx.x & 31, ty = threadIdx.x >> 5;
  const size_t c0 = (size_t)blockIdx.x * 32, r0 = (size_t)blockIdx.y * 32;
#pragma unroll
  for (int i = 0; i < 4; i++)
    tile[ty + i * 8][tx] = src[(r0 + ty + i * 8) * C + c0 + tx];
  __syncthreads();
#pragma unroll
  for (int i = 0; i < 4; i++) {
    int c = ty + i * 8;
    dst[(c0 + c) * R + r0 + tx] = f2bf_bits(tile[tx][c]);
  }
}

// ---------------- LayerNorm: x[row][1024] f32 -> out bf16
__global__ __launch_bounds__(256) void ln_k(const float* __restrict__ x,
                                            const float* __restrict__ g,
                                            const float* __restrict__ be,
                                            unsigned short* __restrict__ o) {
  const int row = blockIdx.x, tid = threadIdx.x;
  const float4 v = ((const float4*)(x + (size_t)row * 1024))[tid];
  float s = v.x + v.y + v.z + v.w;
  float s2 = v.x * v.x + v.y * v.y + v.z * v.z + v.w * v.w;
#pragma unroll
  for (int m = 1; m < 64; m <<= 1) {
    s += __shfl_xor(s, m);
    s2 += __shfl_xor(s2, m);
  }
  __shared__ float red[8];
  const int w = tid >> 6;
  if ((tid & 63) == 0) { red[w] = s; red[4 + w] = s2; }
  __syncthreads();
  s = red[0] + red[1] + red[2] + red[3];
  s2 = red[4] + red[5] + red[6] + red[7];
  const float mu = s * (1.f / 1024.f);
  const float rs_ = rsqrtf(s2 * (1.f / 1024.f) - mu * mu + 1e-5f);
  const float4 gg = ((const float4*)g)[tid];
  const float4 bb = ((const float4*)be)[tid];
  u16x4 pack;
  pack.x = f2bf_bits((v.x - mu) * rs_ * gg.x + bb.x);
  pack.y = f2bf_bits((v.y - mu) * rs_ * gg.y + bb.y);
  pack.z = f2bf_bits((v.z - mu) * rs_ * gg.z + bb.z);
  pack.w = f2bf_bits((v.w - mu) * rs_ * gg.w + bb.w);
  *(u16x4*)(o + (size_t)row * 1024 + tid * 4) = pack;
}

// ---------------- GEMM: C[M][N] = epi(A[M][K(row stride)] @ Bt[N][K]^T ...)
// EPI 0: bf16 store. 1: +bias +res(f32), f32 store. 2: +bias, relu, bf16 store.
// EPI 3: bf16 PARTIAL store at z-slice offset (split-K; K-chunk = KL).
// Counted-vmcnt double-buffered pipeline (T3/T4) + XCD swizzle (T1) + setprio (T5).
template <int EPI>
__global__ __launch_bounds__(256) void gemm_bt(
    const unsigned short* __restrict__ A, const unsigned short* __restrict__ Bt,
    const float* __restrict__ bias, const float* __restrict__ res,
    void* __restrict__ Cv, int M, int N, int K, int KL) {
  __shared__ __align__(16) unsigned short As[2][128 * 64];
  __shared__ __align__(16) unsigned short Bs[2][128 * 64];
  const int tid = threadIdx.x, lane = tid & 63, w = tid >> 6;
  const int lo = lane & 15, hi = lane >> 4;
  const int l8 = lane >> 3, l7 = lane & 7;
  const int scol = ((l7 ^ l8) << 3);  // swizzled source col (elements)
  // T1: XCD-aware block swizzle (per z-slice; nwg % 8 == 0 for all our grids)
  const int nwg = gridDim.x * gridDim.y;
  int bid = blockIdx.y * gridDim.x + blockIdx.x;
  if ((nwg & 7) == 0) bid = (bid & 7) * (nwg >> 3) + (bid >> 3);
  const int bx = bid % gridDim.x, by = bid / gridDim.x;
  const size_t rowBase = (size_t)by * 128;
  const size_t colBase = (size_t)bx * 128;
  const int kOff = blockIdx.z * KL;
  f32x4 acc[4][4];
#pragma unroll
  for (int i = 0; i < 4; i++)
#pragma unroll
    for (int j = 0; j < 4; j++) acc[i][j] = (f32x4){0.f, 0.f, 0.f, 0.f};
  const int wr = (w >> 1) * 64, wc = (w & 1) * 64;
  const unsigned short* aSrc = A + (rowBase + (size_t)w * 32 + l8) * K + scol + kOff;
  const unsigned short* bSrc = Bt + (colBase + (size_t)w * 32 + l8) * K + scol + kOff;

  const int NT = KL >> 6;
  // stage K-tile t into LDS buffer buf (8 gload16 per thread)
  auto stage = [&](int t, int buf) {
    const int kb = t << 6;
#pragma unroll
    for (int c = 0; c < 4; c++) {
      gload16(aSrc + (size_t)c * 8 * K + kb, &As[buf][(w * 4 + c) * 512]);
      gload16(bSrc + (size_t)c * 8 * K + kb, &Bs[buf][(w * 4 + c) * 512]);
    }
  };

  // prologue: tiles 0 and 1 in flight; wait for tile 0 (8 of tile 1 remain)
  stage(0, 0);
  stage(1, 1);
  asm volatile("s_waitcnt vmcnt(8)" ::: "memory");
  __builtin_amdgcn_s_barrier();

  for (int t = 0; t < NT; ++t) {
    const int cur = t & 1;
    const char* asb = (const char*)As[cur];
    const char* bsb = (const char*)Bs[cur];
    __builtin_amdgcn_s_setprio(1);
#pragma unroll
    for (int ks = 0; ks < 2; ks++) {
      bf16x8 af[4], bfr[4];
      const int kbyte = ks * 64 + (hi << 4);
#pragma unroll
      for (int i = 0; i < 4; i++) {
        const int ar = wr + i * 16 + lo;
        af[i] = *(const bf16x8*)(asb + ar * 128 + (kbyte ^ ((ar & 7) << 4)));
        const int br = wc + i * 16 + lo;
        bfr[i] = *(const bf16x8*)(bsb + br * 128 + (kbyte ^ ((br & 7) << 4)));
      }
#pragma unroll
      for (int i = 0; i < 4; i++)
#pragma unroll
        for (int j = 0; j < 4; j++)
          acc[i][j] = __builtin_amdgcn_mfma_f32_16x16x32_bf16(af[i], bfr[j], acc[i][j], 0, 0, 0);
    }
    __builtin_amdgcn_s_setprio(0);
    // all my LDS reads complete (data in regs) before signaling done-with-buf[cur]
    asm volatile("s_waitcnt lgkmcnt(0)" ::: "memory");
    __builtin_amdgcn_s_barrier();  // B1: everyone done reading buf[cur]
    if (t + 2 < NT) {
      stage(t + 2, cur);
      // wait tile t+1's 8 loads (oldest); tile t+2's 8 stay in flight
      asm volatile("s_waitcnt vmcnt(8)" ::: "memory");
    } else {
      asm volatile("s_waitcnt vmcnt(0)" ::: "memory");
    }
    __builtin_amdgcn_s_barrier();  // B2: buf[cur^1] fully staged for all waves
  }

  const size_t zOff = (size_t)blockIdx.z * M * N;
#pragma unroll
  for (int i = 0; i < 4; i++) {
#pragma unroll
    for (int r = 0; r < 4; r++) {
      const size_t row = rowBase + wr + i * 16 + hi * 4 + r;
#pragma unroll
      for (int j = 0; j < 4; j++) {
        const size_t col = colBase + wc + j * 16 + lo;
        float v = acc[i][j][r];
        if (EPI == 1) {
          ((float*)Cv)[row * N + col] = v + bias[col] + res[row * N + col];
        } else if (EPI == 2) {
          ((unsigned short*)Cv)[row * N + col] = f2bf_bits(fmaxf(v + bias[col], 0.f));
        } else if (EPI == 3) {
          ((unsigned short*)Cv)[zOff + row * N + col] = f2bf_bits(v);
        } else {
          ((unsigned short*)Cv)[row * N + col] = f2bf_bits(v);
        }
      }
    }
  }
}

// ---------------- split-K reduce for FF2: out = sum(4 bf16 partials) + bias + res
__global__ __launch_bounds__(256) void ff2red(const unsigned short* __restrict__ p,
                                              const float* __restrict__ bias,
                                              const float* __restrict__ res,
                                              float* __restrict__ out) {
  const size_t i = ((size_t)blockIdx.x * 256 + threadIdx.x) * 8;
  const int col = (int)(i & 1023);
  const float4 b0 = *(const float4*)(bias + col);
  const float4 b1 = *(const float4*)(bias + col + 4);
  const float4 r0 = *(const float4*)(res + i);
  const float4 r1 = *(const float4*)(res + i + 4);
  float acc[8] = {b0.x + r0.x, b0.y + r0.y, b0.z + r0.z, b0.w + r0.w,
                  b1.x + r1.x, b1.y + r1.y, b1.z + r1.z, b1.w + r1.w};
#pragma unroll
  for (int z = 0; z < 4; z++) {
    const u16x8 pv = *(const u16x8*)(p + (size_t)z * 4194304 + i);
#pragma unroll
    for (int j = 0; j < 8; j++) acc[j] += __uint_as_float((unsigned)pv[j] << 16);
  }
  float4 o0 = {acc[0], acc[1], acc[2], acc[3]};
  float4 o1 = {acc[4], acc[5], acc[6], acc[7]};
  *(float4*)(out + i) = o0;
  *(float4*)(out + i + 4) = o1;
}

// ---------------- flash attention: grid (S/64, H, N); 4 waves, 16 q-rows each.
// Swapped QK^T (T12); softmax lane-local; P->PV via cvt_pk + permlane32_swap.
// V staging: in-register 4x4 transpose (v_perm) -> 4x ds_write_b64 (LDS-pipe cut).
__global__ __launch_bounds__(256) void attn_k(const unsigned short* __restrict__ Q,
                                              const unsigned short* __restrict__ K,
                                              const unsigned short* __restrict__ V,
                                              unsigned short* __restrict__ O) {
  __shared__ __align__(16) unsigned short Ks[2][64 * 64];
  __shared__ __align__(16) unsigned short Vt[2][64 * 64];  // Vt[d][kv] (swizzled)
  const int tid = threadIdx.x, lane = tid & 63, w = tid >> 6;
  const int lo = lane & 15, hi = lane >> 4;
  const int l8 = lane >> 3, l7 = lane & 7;
  const int scol = ((l7 ^ l8) << 3);
  const int h = blockIdx.y, n = blockIdx.z;
  const size_t tRow0 = (size_t)n * 2048;
  const int colBase = h * 64;
  const int LD = 3072;
  const float SC = 0.125f * 1.44269504f;  // (1/sqrt(64)) * log2(e)

  // Q fragments (B-operand: col=q=lo, k=d contiguous)
  const unsigned short* qrow = Q + (tRow0 + blockIdx.x * 64 + w * 16 + lo) * LD + colBase;
  const bf16x8 qf0 = *(const bf16x8*)(qrow + hi * 8);
  const bf16x8 qf1 = *(const bf16x8*)(qrow + 32 + hi * 8);
  float m2 = -1e30f, l_r = 0.f;  // per-lane, for q-row = w*16 + lo
  f32x4 oacc[4];
#pragma unroll
  for (int d = 0; d < 4; d++) oacc[d] = (f32x4){0.f, 0.f, 0.f, 0.f};

  // per-thread V staging coords: 4x4 block (rows kvg*4.., cols dgi*4..)
  const int kvg = tid >> 4, dgi = tid & 15;
  const unsigned short* vsrc = V + (tRow0 + (size_t)kvg * 4) * LD + colBase + dgi * 4;
  // per-thread K staging base: wave w owns rows w*16 .. w*16+15 (2 chunks of 8)
  const unsigned short* kbase = K + (tRow0 + (size_t)w * 16 + l8) * LD + colBase + scol;

  // in-register 4x4 bf16 transpose + swizzled b64 writes
  auto vwrite = [&](char* vt, uint2 R0, uint2 R1, uint2 R2, uint2 R3) {
#pragma unroll
    for (int j = 0; j < 4; j++) {
      const unsigned sel = (j & 1) ? 0x03020706u : 0x01000504u;
      const unsigned s0 = (j >= 2) ? R0.y : R0.x;
      const unsigned s1 = (j >= 2) ? R1.y : R1.x;
      const unsigned s2 = (j >= 2) ? R2.y : R2.x;
      const unsigned s3 = (j >= 2) ? R3.y : R3.x;
      uint2 cw;
      cw.x = __builtin_amdgcn_perm(s0, s1, sel);  // (V[kv+0][d], V[kv+1][d])
      cw.y = __builtin_amdgcn_perm(s2, s3, sel);  // (V[kv+2][d], V[kv+3][d])
      const int d = dgi * 4 + j;
      *(uint2*)(vt + d * 128 + ((kvg * 8) ^ ((d & 7) << 4))) = cw;
    }
  };

  // ---- prologue: stage tile 0 into buffer 0
  uint2 R0 = *(const uint2*)(vsrc);
  uint2 R1 = *(const uint2*)(vsrc + LD);
  uint2 R2 = *(const uint2*)(vsrc + 2 * LD);
  uint2 R3 = *(const uint2*)(vsrc + 3 * LD);
#pragma unroll
  for (int c = 0; c < 2; c++)
    gload16(kbase + (size_t)c * 8 * LD, &Ks[0][(w * 2 + c) * 512]);
  vwrite((char*)Vt[0], R0, R1, R2, R3);
  __syncthreads();

  for (int t = 0; t < 32; ++t) {
    const int cur = t & 1;
    // ---- issue next-tile loads early (hide under compute)
    if (t < 31) {
      const unsigned short* vs = vsrc + (size_t)(t + 1) * 64 * LD;
      R0 = *(const uint2*)(vs);
      R1 = *(const uint2*)(vs + LD);
      R2 = *(const uint2*)(vs + 2 * LD);
      R3 = *(const uint2*)(vs + 3 * LD);
#pragma unroll
      for (int c = 0; c < 2; c++)
        gload16(kbase + ((size_t)(t + 1) * 64 + c * 8) * LD, &Ks[cur ^ 1][(w * 2 + c) * 512]);
    }
    // ---- swapped QK^T from Ks[cur]: s[f][r] = P[kv=f*16+hi*4+r][q=lo]
    f32x4 s[4];
    const char* ksb = (const char*)Ks[cur];
    __builtin_amdgcn_s_setprio(1);
#pragma unroll
    for (int f = 0; f < 4; f++) {
      const int kr = f * 16 + lo;
      const bf16x8 b0 = *(const bf16x8*)(ksb + kr * 128 + ((hi * 16) ^ ((kr & 7) << 4)));
      const bf16x8 b1 = *(const bf16x8*)(ksb + kr * 128 + ((64 + hi * 16) ^ ((kr & 7) << 4)));
      s[f] = __builtin_amdgcn_mfma_f32_16x16x32_bf16(b0, qf0, (f32x4){0.f, 0.f, 0.f, 0.f}, 0, 0, 0);
      s[f] = __builtin_amdgcn_mfma_f32_16x16x32_bf16(b1, qf1, s[f], 0, 0, 0);
    }
    __builtin_amdgcn_s_setprio(0);
    // ---- softmax, lane-local for q=lo; reduce across hi-groups on VALU pipe
    float mx = fmaxf(fmaxf(fmaxf(s[0][0], s[0][1]), fmaxf(s[0][2], s[0][3])),
                     fmaxf(fmaxf(s[1][0], s[1][1]), fmaxf(s[1][2], s[1][3])));
    mx = fmaxf(mx, fmaxf(fmaxf(fmaxf(s[2][0], s[2][1]), fmaxf(s[2][2], s[2][3])),
                         fmaxf(fmaxf(s[3][0], s[3][1]), fmaxf(s[3][2], s[3][3]))));
    mx = red16_max(mx);
    mx = red32_max(mx);
    const float mx2v = mx * SC;
    if (__any(mx2v > m2 + 8.f)) {  // defer-max (T13)
      const float mn = fmaxf(m2, mx2v);
      const float al = exp2_amd(m2 - mn);
      l_r *= al;
      m2 = mn;
#pragma unroll
      for (int r = 0; r < 4; r++) {
        const float alr = __shfl(al, hi * 4 + r);  // al for q-row hi*4+r
#pragma unroll
        for (int d = 0; d < 4; d++) oacc[d][r] *= alr;
      }
    }
    // ---- P = exp2(s*SC - m2); lane-partial l; pack to bf16 pairs
    float p[4][4];
    float lsum = 0.f;
#pragma unroll
    for (int f = 0; f < 4; f++)
#pragma unroll
      for (int r = 0; r < 4; r++) {
        p[f][r] = exp2_amd(fmaf(s[f][r], SC, -m2));
        lsum += p[f][r];
      }
    l_r += lsum;
    unsigned W2[4][2];
#pragma unroll
    for (int f = 0; f < 4; f++) {
      W2[f][0] = cvt_pk_bf16(p[f][0], p[f][1]);
      W2[f][1] = cvt_pk_bf16(p[f][2], p[f][3]);
    }
    // ---- redistribute P to A-fragment layout + PV
    __builtin_amdgcn_s_setprio(1);
#pragma unroll
    for (int ks = 0; ks < 2; ks++) {
      unsigned wa[2], wb[2];
#pragma unroll
      for (int hh = 0; hh < 2; hh++) {
        unsigned X = W2[ks * 2][hh], Y = W2[ks * 2 + 1][hh];
        asm("v_permlane32_swap_b32 %0, %1" : "+v"(X), "+v"(Y));
        // X = [Xlo, Ylo], Y = [Xhi, Yhi]
        const unsigned Bx = __shfl_xor((int)Y, 16);
        const unsigned Ax = __shfl_xor((int)X, 16);
        wa[hh] = (hi & 1) ? Bx : X;
        wb[hh] = (hi & 1) ? Y : Ax;
      }
      union { unsigned u[4]; bf16x8 v; } apu;
      apu.u[0] = wa[0]; apu.u[1] = wa[1]; apu.u[2] = wb[0]; apu.u[3] = wb[1];
      const int kbyte = ks * 64 + (hi << 4);
#pragma unroll
      for (int d = 0; d < 4; d++) {
        const int dr = d * 16 + lo;
        const bf16x8 bv = *(const bf16x8*)((const char*)Vt[cur] + dr * 128 + (kbyte ^ ((dr & 7) << 4)));
        oacc[d] = __builtin_amdgcn_mfma_f32_16x16x32_bf16(apu.v, bv, oacc[d], 0, 0, 0);
      }
    }
    __builtin_amdgcn_s_setprio(0);
    // ---- write next V tile into the other buffer (reg loads arrived by now)
    if (t < 31) vwrite((char*)Vt[cur ^ 1], R0, R1, R2, R3);
    __syncthreads();  // staging of next tile complete; cur reads done
  }
  // ---- epilogue: reduce l across hi-groups (q=lo), broadcast inv to oacc rows
  float l = red32_sum(red16_sum(l_r));
  const float inv = 1.f / l;  // for q-row = w*16 + lo
#pragma unroll
  for (int r = 0; r < 4; r++) {
    const float invr = __shfl(inv, hi * 4 + r);
    const size_t row = tRow0 + blockIdx.x * 64 + w * 16 + hi * 4 + r;
#pragma unroll
    for (int d = 0; d < 4; d++)
      O[row * 1024 + colBase + d * 16 + lo] = f2bf_bits(oacc[d][r] * invr);
  }
}

extern "C" void kernel_launch(void* const* d_in, const int* in_sizes, int n_in,
                              void* d_out, int out_size, void* d_ws, size_t ws_size,
                              hipStream_t stream) {
  (void)in_sizes; (void)n_in; (void)out_size; (void)ws_size;
  const float* x   = (const float*)d_in[0];
  const float* w_q = (const float*)d_in[2];
  const float* w_k = (const float*)d_in[3];
  const float* w_v = (const float*)d_in[4];
  const float* w_0 = (const float*)d_in[5];
  const float* b_0 = (const float*)d_in[6];
  const float* w_1 = (const float*)d_in[7];
  const float* b_1 = (const float*)d_in[8];
  const float* w_2 = (const float*)d_in[9];
  const float* b_2 = (const float*)d_in[10];
  const float* g_1 = (const float*)d_in[11];
  const float* be_1 = (const float*)d_in[12];
  const float* g_2 = (const float*)d_in[13];
  const float* be_2 = (const float*)d_in[14];

  char* ws = (char*)d_ws;
  size_t off = 0;
  auto alloc = [&](size_t bytes) {
    void* p = ws + off;
    off += (bytes + 255) & ~(size_t)255;
    return p;
  };
  const size_t MB = 1024 * 1024;
  // wt_q/wt_k/wt_v contiguous -> fused [3072][1024] Bt for the QKV GEMM
  unsigned short* wt_q = (unsigned short*)alloc(2 * MB);
  unsigned short* wt_k = (unsigned short*)alloc(2 * MB);
  unsigned short* wt_v = (unsigned short*)alloc(2 * MB);
  unsigned short* wt_0 = (unsigned short*)alloc(2 * MB);
  unsigned short* wt_1 = (unsigned short*)alloc(8 * MB);   // [4096][1024]
  unsigned short* wt_2 = (unsigned short*)alloc(8 * MB);   // [1024][4096]
  unsigned short* xn   = (unsigned short*)alloc(8 * MB);   // [4096][1024]
  unsigned short* qkv  = (unsigned short*)alloc(24 * MB);  // [4096][3072]
  unsigned short* aO   = (unsigned short*)alloc(8 * MB);
  float*          x1f  = (float*)alloc(16 * MB);           // [4096][1024] f32
  unsigned short* ff1  = (unsigned short*)alloc(32 * MB);  // [4096][4096]
  // FF2 split-K partials (4 x [4096][1024] bf16 = 32MB) reuse qkv+aO (dead by then)
  unsigned short* part = qkv;

  // weights -> bf16 transposed
  wconv_t<<<dim3(32, 32), 256, 0, stream>>>(w_q, wt_q, 1024, 1024);
  wconv_t<<<dim3(32, 32), 256, 0, stream>>>(w_k, wt_k, 1024, 1024);
  wconv_t<<<dim3(32, 32), 256, 0, stream>>>(w_v, wt_v, 1024, 1024);
  wconv_t<<<dim3(32, 32), 256, 0, stream>>>(w_0, wt_0, 1024, 1024);
  wconv_t<<<dim3(128, 32), 256, 0, stream>>>(w_1, wt_1, 1024, 4096);
  wconv_t<<<dim3(32, 128), 256, 0, stream>>>(w_2, wt_2, 4096, 1024);

  // LN1
  ln_k<<<4096, 256, 0, stream>>>(x, g_1, be_1, xn);
  // fused QKV projection: [4096][1024] @ [3072][1024]^T -> [4096][3072]
  gemm_bt<0><<<dim3(24, 32), 256, 0, stream>>>(xn, wt_q, nullptr, nullptr, qkv, 4096, 3072, 1024, 1024);
  // attention (Q/K/V columns of the fused buffer, row stride 3072)
  attn_k<<<dim3(32, 16, 2), 256, 0, stream>>>(qkv, qkv + 1024, qkv + 2048, aO);
  // output proj + residual -> x1 (f32)
  gemm_bt<1><<<dim3(8, 32), 256, 0, stream>>>(aO, wt_0, b_0, x, x1f, 4096, 1024, 1024, 1024);
  // LN2
  ln_k<<<4096, 256, 0, stream>>>(x1f, g_2, be_2, xn);
  // FF1 + relu
  gemm_bt<2><<<dim3(32, 32), 256, 0, stream>>>(xn, wt_1, b_1, nullptr, ff1, 4096, 4096, 1024, 1024);
  // FF2 split-K=4 -> bf16 partials, then fused reduce (+bias +residual) -> out f32
  gemm_bt<3><<<dim3(8, 32, 4), 256, 0, stream>>>(ff1, wt_2, nullptr, nullptr, part, 4096, 1024, 4096, 1024);
  ff2red<<<2048, 256, 0, stream>>>(part, b_2, x1f, (float*)d_out);
}